// Round 3
// baseline (323.109 us; speedup 1.0000x reference)
//
#include <hip/hip_runtime.h>
#include <hip/hip_bf16.h>

typedef __hip_bfloat16 bf16;
typedef unsigned short ushortT;

#define N_NODES 384
#define KNBR 60
#define SUBK 20
#define NHEAD 4
#define NEDGE (N_NODES * KNBR)
#define EPSC 1e-8f
#define INV_SQRT_CZ 0.08838834764831845f   // 1/sqrt(128)
#define MU_STEP (20.0f / 63.0f)            // linspace(0,20,64) step
#define INV_SIGMA 3.2f                     // 1/(20/64)

__device__ __forceinline__ float bf2f(unsigned int u) {
  return __uint_as_float(u << 16);
}
__device__ __forceinline__ void storeC(float v, float* p) { *p = v; }
__device__ __forceinline__ void storeC(float v, ushortT* p) {
  union { float f; unsigned int u; } cvt;
  cvt.f = v;
  unsigned int x = cvt.u;
  unsigned int rounded = (x + 0x7fffu + ((x >> 16) & 1u)) >> 16;  // RNE
  *p = (ushortT)rounded;
}

// g[n][0:4] = nf[n] . W_gate[0:128,:] ; g[n][4:8] = nf[n] . W_gate[128:256,:]
__global__ void gate_proj_kernel(const float* __restrict__ nf, const float* __restrict__ Wg,
                                 float* __restrict__ g) {
  int n = blockIdx.x, t = threadIdx.x;  // 64 threads
  float a = nf[n * 128 + t];
  float b = nf[n * 128 + 64 + t];
  float acc[8];
#pragma unroll
  for (int h = 0; h < 4; ++h) {
    acc[h]     = a * Wg[t * 4 + h]         + b * Wg[(t + 64) * 4 + h];
    acc[4 + h] = a * Wg[(128 + t) * 4 + h] + b * Wg[(192 + t) * 4 + h];
  }
#pragma unroll
  for (int i = 0; i < 8; ++i)
#pragma unroll
    for (int off = 32; off >= 1; off >>= 1) acc[i] += __shfl_xor(acc[i], off, 64);
  if (t == 0) {
#pragma unroll
    for (int i = 0; i < 8; ++i) g[n * 8 + i] = acc[i];
  }
}

// Pack [W_qk | W_v] -> Wc (128x384 f32), [b_qk | b_v] -> bc (384 f32)
__global__ void pack_w_kernel(const float* __restrict__ Wqk, const float* __restrict__ bqk,
                              const float* __restrict__ Wv, const float* __restrict__ bv,
                              float* __restrict__ Wc, float* __restrict__ bc) {
  int i = blockIdx.x * 256 + threadIdx.x;
  if (i < 128 * 384) {
    int r = i / 384, c = i % 384;
    Wc[i] = (c < 256) ? Wqk[r * 256 + c] : Wv[r * 128 + (c - 256)];
  }
  if (i < 384) bc[i] = (i < 256) ? bqk[i] : bv[i - 256];
}

// C[M][N] = A[M][K] * B[K][N] + bias[N], f32 accumulate. BM=BN=64, BK=16, 256 thr, 4x4 microtile.
template <typename TC>
__global__ __launch_bounds__(256) void sgemm_bias_kernel(const float* __restrict__ A,
                                                         const float* __restrict__ B,
                                                         const float* __restrict__ bias,
                                                         TC* __restrict__ C, int M, int N, int Kd) {
  __shared__ float As[16][65];
  __shared__ float Bs[16][65];
  int tid = threadIdx.x;
  int tm = tid / 16, tn = tid % 16;
  int row0 = blockIdx.y * 64, col0 = blockIdx.x * 64;
  float acc[4][4] = {};
  for (int k0 = 0; k0 < Kd; k0 += 16) {
    for (int i = tid; i < 64 * 16; i += 256) {
      int m = i / 16, kk = i % 16;
      As[kk][m] = A[(size_t)(row0 + m) * Kd + k0 + kk];
    }
    for (int i = tid; i < 16 * 64; i += 256) {
      int kk = i / 64, nn = i % 64;
      Bs[kk][nn] = B[(size_t)(k0 + kk) * N + col0 + nn];
    }
    __syncthreads();
#pragma unroll
    for (int kk = 0; kk < 16; ++kk) {
      float a[4], b[4];
#pragma unroll
      for (int i = 0; i < 4; ++i) a[i] = As[kk][tm * 4 + i];
#pragma unroll
      for (int j = 0; j < 4; ++j) b[j] = Bs[kk][tn * 4 + j];
#pragma unroll
      for (int i = 0; i < 4; ++i)
#pragma unroll
        for (int j = 0; j < 4; ++j) acc[i][j] += a[i] * b[j];
    }
    __syncthreads();
  }
#pragma unroll
  for (int i = 0; i < 4; ++i)
#pragma unroll
    for (int j = 0; j < 4; ++j) {
      int r = row0 + tm * 4 + i, c = col0 + tn * 4 + j;
      storeC(acc[i][j] + bias[c], &C[(size_t)r * N + c]);
    }
}

// One block per node n. LDS: k|v rows (f32) for all 60 neighbors, trans, gate projections.
// 256 threads -> 2 (n,k) pairs per iteration; lane = (h, d) over the 128 output dims.
__global__ __launch_bounds__(256) void attn_kernel(
    const ushortT* __restrict__ qkvb, const float* __restrict__ g,
    const float* __restrict__ node_trans, const int* __restrict__ edge_index,
    const int* __restrict__ sub_idx, const float* __restrict__ W_db,
    const float* __restrict__ b_db, const float* __restrict__ b_gate, float* __restrict__ upd) {
  __shared__ __align__(16) float kv[KNBR * 256];  // [j][0:128]=k, [j][128:256]=v
  __shared__ float trs[KNBR * 3];
  __shared__ float gg[KNBR * 8];  // [j][0:4]=g1(dst), [j][4:8]=g2(dst)
  int n = blockIdx.x, tid = threadIdx.x;
  int e0 = n * KNBR;
  if (tid < KNBR) {
    int dst = edge_index[e0 + tid];
#pragma unroll
    for (int c = 0; c < 3; ++c) trs[tid * 3 + c] = node_trans[dst * 3 + c];
#pragma unroll
    for (int i = 0; i < 8; ++i) gg[tid * 8 + i] = g[dst * 8 + i];
  }
  // stage k|v (256 bf16 per neighbor) as f32 into LDS
  for (int i = tid; i < KNBR * 32; i += 256) {
    int j = i >> 5, c = i & 31;  // c indexes 16B chunks (8 bf16)
    uint4 u = ((const uint4*)(qkvb + (size_t)(e0 + j) * 384 + 128))[c];
    int base = j * 256 + c * 8;
    kv[base + 0] = bf2f(u.x & 0xffffu);  kv[base + 1] = bf2f(u.x >> 16);
    kv[base + 2] = bf2f(u.y & 0xffffu);  kv[base + 3] = bf2f(u.y >> 16);
    kv[base + 4] = bf2f(u.z & 0xffffu);  kv[base + 5] = bf2f(u.z >> 16);
    kv[base + 6] = bf2f(u.w & 0xffffu);  kv[base + 7] = bf2f(u.w >> 16);
  }
  __syncthreads();

  int lt = tid & 127;
  int h = lt >> 5, d = tid & 31;
  float wdb1 = W_db[d * 4 + h];
  float wdb2 = W_db[(d + 32) * 4 + h];
  float bdbh = b_db[h];
  float bgh = b_gate[h];

  for (int k0 = 0; k0 < KNBR; k0 += 2) {
    int k = k0 + (tid >> 7);
    float q = bf2f((unsigned int)qkvb[(size_t)(e0 + k) * 384 + lt]);
    float g1h = gg[k * 8 + h];
    float t1x = trs[k * 3 + 0], t1y = trs[k * 3 + 1], t1z = trs[k * 3 + 2];
    float logit[SUBK];
    int js[SUBK];
#pragma unroll
    for (int s = 0; s < SUBK; ++s) {
      int j = sub_idx[(e0 + k) * SUBK + s];
      js[s] = j;
      float gate = g1h + gg[j * 8 + 4 + h] + bgh;
      gate = 1.0f / (1.0f + __expf(-gate));
      float dx = t1x - trs[j * 3 + 0] + EPSC;
      float dy = t1y - trs[j * 3 + 1] + EPSC;
      float dz = t1z - trs[j * 3 + 2] + EPSC;
      float dist = sqrtf(dx * dx + dy * dy + dz * dz);
      float a1 = (dist - d * MU_STEP) * INV_SIGMA;
      float a2 = (dist - (d + 32) * MU_STEP) * INV_SIGMA;
      float part = q * kv[j * 256 + lt] * INV_SQRT_CZ +
                   gate * (__expf(-a1 * a1) * wdb1 + __expf(-a2 * a2) * wdb2);
#pragma unroll
      for (int off = 16; off >= 1; off >>= 1) part += __shfl_xor(part, off, 32);
      logit[s] = part + gate * bdbh;
    }
    float m = logit[0];
#pragma unroll
    for (int s = 1; s < SUBK; ++s) m = fmaxf(m, logit[s]);
    float den = 0.f;
#pragma unroll
    for (int s = 0; s < SUBK; ++s) {
      logit[s] = __expf(logit[s] - m);
      den += logit[s];
    }
    float inv = 1.0f / den;
    float acc = 0.f;
#pragma unroll
    for (int s = 0; s < SUBK; ++s) acc += logit[s] * kv[js[s] * 256 + 128 + lt];
    upd[(size_t)(e0 + k) * 128 + lt] = acc * inv;
  }
}

extern "C" void kernel_launch(void* const* d_in, const int* in_sizes, int n_in, void* d_out,
                              int out_size, void* d_ws, size_t ws_size, hipStream_t stream) {
  const float* nf  = (const float*)d_in[0];
  const float* nt  = (const float*)d_in[1];
  const float* ef  = (const float*)d_in[2];
  const int*   ei  = (const int*)d_in[3];
  const int*   si  = (const int*)d_in[4];
  const float* Wg  = (const float*)d_in[5];
  const float* bg  = (const float*)d_in[6];
  const float* Wdb = (const float*)d_in[7];
  const float* bdb = (const float*)d_in[8];
  const float* Wqk = (const float*)d_in[9];
  const float* bqk = (const float*)d_in[10];
  const float* Wv  = (const float*)d_in[11];
  const float* bv  = (const float*)d_in[12];
  const float* Wout = (const float*)d_in[13];
  const float* bout = (const float*)d_in[14];
  float* out = (float*)d_out;  // reference output dtype is float32

  // ws layout:
  float* g    = (float*)d_ws;              // 3072 f32
  float* Wc   = g + 3072;                  // 49152 f32
  float* bc   = Wc + 49152;                // 384 f32
  ushortT* qkvb = (ushortT*)(bc + 384);    // 23040*384 bf16 (q|k|v per edge)
  float* upd  = (float*)(qkvb + (size_t)NEDGE * 384);  // 23040*128 f32

  gate_proj_kernel<<<dim3(N_NODES), dim3(64), 0, stream>>>(nf, Wg, g);
  pack_w_kernel<<<dim3(192), dim3(256), 0, stream>>>(Wqk, bqk, Wv, bv, Wc, bc);
  sgemm_bias_kernel<ushortT>
      <<<dim3(6, 360), dim3(256), 0, stream>>>(ef, Wc, bc, qkvb, NEDGE, 384, 128);
  attn_kernel<<<dim3(N_NODES), dim3(256), 0, stream>>>(qkvb, g, nt, ei, si, Wdb, bdb, bg, upd);
  sgemm_bias_kernel<float>
      <<<dim3(2, 360), dim3(256), 0, stream>>>(upd, Wout, bout, out, NEDGE, 128, 128);
}

// Round 4
// 128.744 us; speedup vs baseline: 2.5097x; 2.5097x over previous
//
#include <hip/hip_runtime.h>
#include <hip/hip_bf16.h>

typedef __hip_bfloat16 bf16;
typedef unsigned short ushortT;

#define N_NODES 384
#define KNBR 60
#define SUBK 20
#define NHEAD 4
#define NEDGE (N_NODES * KNBR)
#define EPSC 1e-8f
#define INV_SQRT_CZ 0.08838834764831845f   // 1/sqrt(128)
#define MU_STEP (20.0f / 63.0f)            // linspace(0,20,64) step
#define INV_SIGMA 3.2f                     // 1/(20/64)
#define KC 16                              // k-chunk per block
#define NSPLIT 4                           // ceil(60/16)

__device__ __forceinline__ float bf2f(unsigned int u) {
  return __uint_as_float(u << 16);
}
__device__ __forceinline__ void storeC(float v, float* p) { *p = v; }
__device__ __forceinline__ void storeC(float v, ushortT* p) {
  union { float f; unsigned int u; } cvt;
  cvt.f = v;
  unsigned int x = cvt.u;
  unsigned int rounded = (x + 0x7fffu + ((x >> 16) & 1u)) >> 16;  // RNE
  *p = (ushortT)rounded;
}

// g[n][0:4] = nf[n] . W_gate[0:128,:] ; g[n][4:8] = nf[n] . W_gate[128:256,:]
__global__ void gate_proj_kernel(const float* __restrict__ nf, const float* __restrict__ Wg,
                                 float* __restrict__ g) {
  int n = blockIdx.x, t = threadIdx.x;  // 64 threads
  float a = nf[n * 128 + t];
  float b = nf[n * 128 + 64 + t];
  float acc[8];
#pragma unroll
  for (int h = 0; h < 4; ++h) {
    acc[h]     = a * Wg[t * 4 + h]         + b * Wg[(t + 64) * 4 + h];
    acc[4 + h] = a * Wg[(128 + t) * 4 + h] + b * Wg[(192 + t) * 4 + h];
  }
#pragma unroll
  for (int i = 0; i < 8; ++i)
#pragma unroll
    for (int off = 32; off >= 1; off >>= 1) acc[i] += __shfl_xor(acc[i], off, 64);
  if (t == 0) {
#pragma unroll
    for (int i = 0; i < 8; ++i) g[n * 8 + i] = acc[i];
  }
}

// Pack [W_qk | W_v] -> Wc (128x384 f32), [b_qk | b_v] -> bc (384 f32)
__global__ void pack_w_kernel(const float* __restrict__ Wqk, const float* __restrict__ bqk,
                              const float* __restrict__ Wv, const float* __restrict__ bv,
                              float* __restrict__ Wc, float* __restrict__ bc) {
  int i = blockIdx.x * 256 + threadIdx.x;
  if (i < 128 * 384) {
    int r = i / 384, c = i % 384;
    Wc[i] = (c < 256) ? Wqk[r * 256 + c] : Wv[r * 128 + (c - 256)];
  }
  if (i < 384) bc[i] = (i < 256) ? bqk[i] : bv[i - 256];
}

// C[M][N] = A[M][K] * B[K][N] + bias[N], f32 accumulate. BM=BN=64, BK=16, 256 thr, 4x4 microtile.
template <typename TC>
__global__ __launch_bounds__(256) void sgemm_bias_kernel(const float* __restrict__ A,
                                                         const float* __restrict__ B,
                                                         const float* __restrict__ bias,
                                                         TC* __restrict__ C, int M, int N, int Kd) {
  __shared__ float As[16][65];
  __shared__ float Bs[16][65];
  int tid = threadIdx.x;
  int tm = tid / 16, tn = tid % 16;
  int row0 = blockIdx.y * 64, col0 = blockIdx.x * 64;
  float acc[4][4] = {};
  for (int k0 = 0; k0 < Kd; k0 += 16) {
    for (int i = tid; i < 64 * 16; i += 256) {
      int m = i / 16, kk = i % 16;
      As[kk][m] = A[(size_t)(row0 + m) * Kd + k0 + kk];
    }
    for (int i = tid; i < 16 * 64; i += 256) {
      int kk = i / 64, nn = i % 64;
      Bs[kk][nn] = B[(size_t)(k0 + kk) * N + col0 + nn];
    }
    __syncthreads();
#pragma unroll
    for (int kk = 0; kk < 16; ++kk) {
      float a[4], b[4];
#pragma unroll
      for (int i = 0; i < 4; ++i) a[i] = As[kk][tm * 4 + i];
#pragma unroll
      for (int j = 0; j < 4; ++j) b[j] = Bs[kk][tn * 4 + j];
#pragma unroll
      for (int i = 0; i < 4; ++i)
#pragma unroll
        for (int j = 0; j < 4; ++j) acc[i][j] += a[i] * b[j];
    }
    __syncthreads();
  }
#pragma unroll
  for (int i = 0; i < 4; ++i)
#pragma unroll
    for (int j = 0; j < 4; ++j) {
      int r = row0 + tm * 4 + i, c = col0 + tn * 4 + j;
      storeC(acc[i][j] + bias[c], &C[(size_t)r * N + c]);
    }
}

// grid (N_NODES, NSPLIT) x 256 threads. Block handles k in [by*KC, by*KC+KC).
// Phase 1: stage kv (bf16), trs, gg. Phase 2: precompute bias[k][s][h] (dist+RBF+gate)
// once per (k,s). Phase 3: lane owns 4 dims of one k; 3-shuffle dot reduce; softmax; PV.
__global__ __launch_bounds__(256) void attn_kernel(
    const ushortT* __restrict__ qkvb, const float* __restrict__ g,
    const float* __restrict__ node_trans, const int* __restrict__ edge_index,
    const int* __restrict__ sub_idx, const float* __restrict__ W_db,
    const float* __restrict__ b_db, const float* __restrict__ b_gate, float* __restrict__ upd) {
  __shared__ __align__(16) ushortT kvb[KNBR * 256];   // [j][0:128]=k, [j][128:256]=v (bf16)
  __shared__ float bias_lds[KC][SUBK][4];
  __shared__ int sub_lds[KC][SUBK];
  __shared__ float trs[KNBR * 3];
  __shared__ float gg[KNBR * 8];
  int n = blockIdx.x, tid = threadIdx.x;
  int k0b = blockIdx.y * KC;
  int e0 = n * KNBR;

  if (tid < KNBR) {
    int dst = edge_index[e0 + tid];
#pragma unroll
    for (int c = 0; c < 3; ++c) trs[tid * 3 + c] = node_trans[dst * 3 + c];
#pragma unroll
    for (int i = 0; i < 8; ++i) gg[tid * 8 + i] = g[dst * 8 + i];
  }
  // stage k|v rows (256 bf16 each) for all 60 neighbors
  for (int i = tid; i < KNBR * 32; i += 256) {
    int j = i >> 5, c = i & 31;
    ((uint4*)kvb)[j * 32 + c] = ((const uint4*)(qkvb + (size_t)(e0 + j) * 384 + 128))[c];
  }
  __syncthreads();

  // precompute bias[k][s][h] = sigmoid(g1+g2+bg) * (rbf(dist)@W_db + b_db)
  float4 bgv = *(const float4*)b_gate;
  float4 bdbv = *(const float4*)b_db;
  for (int p = tid; p < KC * SUBK; p += 256) {
    int kl = p / SUBK, s = p % SUBK;
    int kg = k0b + kl;
    if (kg < KNBR) {
      int j = sub_idx[(size_t)(e0 + kg) * SUBK + s];
      sub_lds[kl][s] = j;
      float dx = trs[kg * 3 + 0] - trs[j * 3 + 0] + EPSC;
      float dy = trs[kg * 3 + 1] - trs[j * 3 + 1] + EPSC;
      float dz = trs[kg * 3 + 2] - trs[j * 3 + 2] + EPSC;
      float dist = sqrtf(dx * dx + dy * dy + dz * dz);
      float a0 = 0.f, a1 = 0.f, a2 = 0.f, a3 = 0.f;
#pragma unroll
      for (int r = 0; r < 64; ++r) {
        float t = (dist - r * MU_STEP) * INV_SIGMA;
        float e = __expf(-t * t);
        float4 w = ((const float4*)W_db)[r];
        a0 += e * w.x; a1 += e * w.y; a2 += e * w.z; a3 += e * w.w;
      }
      float g1 = gg[kg * 8 + 0] + gg[j * 8 + 4 + 0] + bgv.x;
      float g2 = gg[kg * 8 + 1] + gg[j * 8 + 4 + 1] + bgv.y;
      float g3 = gg[kg * 8 + 2] + gg[j * 8 + 4 + 2] + bgv.z;
      float g4 = gg[kg * 8 + 3] + gg[j * 8 + 4 + 3] + bgv.w;
      bias_lds[kl][s][0] = (a0 + bdbv.x) / (1.0f + __expf(-g1));
      bias_lds[kl][s][1] = (a1 + bdbv.y) / (1.0f + __expf(-g2));
      bias_lds[kl][s][2] = (a2 + bdbv.z) / (1.0f + __expf(-g3));
      bias_lds[kl][s][3] = (a3 + bdbv.w) / (1.0f + __expf(-g4));
    }
  }
  __syncthreads();

  // lane layout: k_half=(tid>>5)&1, h=(tid>>3)&3, dq=tid&7 -> dims h*32+dq*4 .. +3
  int h = (tid >> 3) & 3, dq = tid & 7;
  int dim0 = h * 32 + dq * 4;
  for (int ki = 0; ki < KC; ki += 8) {
    int kl = ki + ((tid >> 6) << 1) + ((tid >> 5) & 1);
    int kg = k0b + kl;
    if (kg < KNBR) {
      uint2 qu = *(const uint2*)(qkvb + (size_t)(e0 + kg) * 384 + dim0);
      float q0 = bf2f(qu.x & 0xffffu) * INV_SQRT_CZ, q1 = bf2f(qu.x >> 16) * INV_SQRT_CZ;
      float q2 = bf2f(qu.y & 0xffffu) * INV_SQRT_CZ, q3 = bf2f(qu.y >> 16) * INV_SQRT_CZ;
      float logit[SUBK];
#pragma unroll
      for (int s = 0; s < SUBK; ++s) {
        int j = sub_lds[kl][s];
        uint2 ku = *(const uint2*)(kvb + j * 256 + dim0);
        float part = q0 * bf2f(ku.x & 0xffffu) + q1 * bf2f(ku.x >> 16) +
                     q2 * bf2f(ku.y & 0xffffu) + q3 * bf2f(ku.y >> 16);
        part += __shfl_xor(part, 1);
        part += __shfl_xor(part, 2);
        part += __shfl_xor(part, 4);
        logit[s] = part + bias_lds[kl][s][h];
      }
      float m = logit[0];
#pragma unroll
      for (int s = 1; s < SUBK; ++s) m = fmaxf(m, logit[s]);
      float den = 0.f;
#pragma unroll
      for (int s = 0; s < SUBK; ++s) {
        logit[s] = __expf(logit[s] - m);
        den += logit[s];
      }
      float inv = 1.0f / den;
      float acc0 = 0.f, acc1 = 0.f, acc2 = 0.f, acc3 = 0.f;
#pragma unroll
      for (int s = 0; s < SUBK; ++s) {
        int j = sub_lds[kl][s];
        uint2 vu = *(const uint2*)(kvb + j * 256 + 128 + dim0);
        float w = logit[s];
        acc0 += w * bf2f(vu.x & 0xffffu);
        acc1 += w * bf2f(vu.x >> 16);
        acc2 += w * bf2f(vu.y & 0xffffu);
        acc3 += w * bf2f(vu.y >> 16);
      }
      float4 o;
      o.x = acc0 * inv; o.y = acc1 * inv; o.z = acc2 * inv; o.w = acc3 * inv;
      *(float4*)(upd + (size_t)(e0 + kg) * 128 + dim0) = o;
    }
  }
}

extern "C" void kernel_launch(void* const* d_in, const int* in_sizes, int n_in, void* d_out,
                              int out_size, void* d_ws, size_t ws_size, hipStream_t stream) {
  const float* nf  = (const float*)d_in[0];
  const float* nt  = (const float*)d_in[1];
  const float* ef  = (const float*)d_in[2];
  const int*   ei  = (const int*)d_in[3];
  const int*   si  = (const int*)d_in[4];
  const float* Wg  = (const float*)d_in[5];
  const float* bg  = (const float*)d_in[6];
  const float* Wdb = (const float*)d_in[7];
  const float* bdb = (const float*)d_in[8];
  const float* Wqk = (const float*)d_in[9];
  const float* bqk = (const float*)d_in[10];
  const float* Wv  = (const float*)d_in[11];
  const float* bv  = (const float*)d_in[12];
  const float* Wout = (const float*)d_in[13];
  const float* bout = (const float*)d_in[14];
  float* out = (float*)d_out;  // reference output dtype is float32

  // ws layout:
  float* g    = (float*)d_ws;              // 3072 f32
  float* Wc   = g + 3072;                  // 49152 f32
  float* bc   = Wc + 49152;                // 384 f32
  ushortT* qkvb = (ushortT*)(bc + 384);    // 23040*384 bf16 (q|k|v per edge)
  float* upd  = (float*)(qkvb + (size_t)NEDGE * 384);  // 23040*128 f32

  gate_proj_kernel<<<dim3(N_NODES), dim3(64), 0, stream>>>(nf, Wg, g);
  pack_w_kernel<<<dim3(192), dim3(256), 0, stream>>>(Wqk, bqk, Wv, bv, Wc, bc);
  sgemm_bias_kernel<ushortT>
      <<<dim3(6, 360), dim3(256), 0, stream>>>(ef, Wc, bc, qkvb, NEDGE, 384, 128);
  attn_kernel<<<dim3(N_NODES, NSPLIT), dim3(256), 0, stream>>>(qkvb, g, nt, ei, si, Wdb, bdb, bg, upd);
  sgemm_bias_kernel<float>
      <<<dim3(2, 360), dim3(256), 0, stream>>>(upd, Wout, bout, out, NEDGE, 128, 128);
}

// Round 5
// 65.818 us; speedup vs baseline: 4.9091x; 1.9561x over previous
//
#include <hip/hip_runtime.h>
#include <hip/hip_bf16.h>

typedef __hip_bfloat16 bf16;
typedef unsigned short ushortT;
typedef __attribute__((ext_vector_type(8))) short bf16x8;
typedef __attribute__((ext_vector_type(4))) float f32x4;

#define N_NODES 384
#define KNBR 60
#define SUBK 20
#define NHEAD 4
#define NEDGE (N_NODES * KNBR)
#define EPSC 1e-8f
#define INV_SQRT_CZ 0.08838834764831845f   // 1/sqrt(128)
#define MU_STEP (20.0f / 63.0f)            // linspace(0,20,64) step
#define INV_SIGMA 3.2f                     // 1/(20/64)
#define KC 16                              // k-chunk per attn block
#define NSPLIT 4                           // ceil(60/16)

__device__ __forceinline__ float bf2f(unsigned int u) {
  return __uint_as_float(u << 16);
}
__device__ __forceinline__ ushortT f2bu(float v) {  // f32 -> bf16 bits, RNE
  union { float f; unsigned int u; } c;
  c.f = v;
  return (ushortT)((c.u + 0x7fffu + ((c.u >> 16) & 1u)) >> 16);
}
__device__ __forceinline__ unsigned int pack2bf(float x, float y) {
  return (unsigned int)f2bu(x) | ((unsigned int)f2bu(y) << 16);
}

// g[n][0:4] = nf[n] . W_gate[0:128,:] ; g[n][4:8] = nf[n] . W_gate[128:256,:]
__global__ void gate_proj_kernel(const float* __restrict__ nf, const float* __restrict__ Wg,
                                 float* __restrict__ g) {
  int n = blockIdx.x, t = threadIdx.x;  // 64 threads
  float a = nf[n * 128 + t];
  float b = nf[n * 128 + 64 + t];
  float acc[8];
#pragma unroll
  for (int h = 0; h < 4; ++h) {
    acc[h]     = a * Wg[t * 4 + h]         + b * Wg[(t + 64) * 4 + h];
    acc[4 + h] = a * Wg[(128 + t) * 4 + h] + b * Wg[(192 + t) * 4 + h];
  }
#pragma unroll
  for (int i = 0; i < 8; ++i)
#pragma unroll
    for (int off = 32; off >= 1; off >>= 1) acc[i] += __shfl_xor(acc[i], off, 64);
  if (t == 0) {
#pragma unroll
    for (int i = 0; i < 8; ++i) g[n * 8 + i] = acc[i];
  }
}

// Pack weights into MFMA fragment order (bf16).
// Wp1[((ny*12+nt)*4+t)*512 + l*8 + j] = Bqkv[k=t*32+(l>>4)*8+j][n=ny*192+nt*16+(l&15)]
// Wp2[((nt*4+t))*512 + l*8 + j]       = Wout[k][n=nt*16+(l&15)]
__global__ void pack_w_kernel(const float* __restrict__ Wqk, const float* __restrict__ bqk,
                              const float* __restrict__ Wv, const float* __restrict__ bv,
                              const float* __restrict__ Wout,
                              ushortT* __restrict__ Wp1, ushortT* __restrict__ Wp2,
                              float* __restrict__ bc) {
  int i = blockIdx.x * 256 + threadIdx.x;  // 65536 total
  if (i < 49152) {
    int j = i & 7, l = (i >> 3) & 63, t = (i >> 9) & 3;
    int nt = (i >> 11) % 12, ny = (i >> 11) / 12;
    int nn = ny * 192 + nt * 16 + (l & 15);
    int k = t * 32 + (l >> 4) * 8 + j;
    float v = (nn < 256) ? Wqk[k * 256 + nn] : Wv[k * 128 + (nn - 256)];
    Wp1[i] = f2bu(v);
  } else {
    int i2 = i - 49152;  // 16384
    int j = i2 & 7, l = (i2 >> 3) & 63, t = (i2 >> 9) & 3, nt = (i2 >> 11);
    int nn = nt * 16 + (l & 15);
    int k = t * 32 + (l >> 4) * 8 + j;
    Wp2[i2] = f2bu(Wout[k * 128 + nn]);
  }
  if (i < 384) bc[i] = (i < 256) ? bqk[i] : bv[i - 256];
}

// qkv projection: C[23040x384] = bf16(ef[23040x128]) x Wp1 + bc, output bf16.
// grid (360, 2), 256 thr. Wave w owns rows bx*64+w*16..+15; by selects 192-col half.
__global__ __launch_bounds__(256) void gemm_qkv_kernel(const float* __restrict__ ef,
                                                       const ushortT* __restrict__ Wp1,
                                                       const float* __restrict__ bc,
                                                       ushortT* __restrict__ qkvb) {
  __shared__ __align__(16) ushortT blds[24576];  // 48 KB: 12 ntiles x 4 ksteps x 64 x 8
  int tid = threadIdx.x;
  int bx = blockIdx.x, by = blockIdx.y;
  const uint4* src = (const uint4*)(Wp1 + by * 24576);
  uint4* dst4 = (uint4*)blds;
#pragma unroll
  for (int i = 0; i < 12; ++i) dst4[tid + i * 256] = src[tid + i * 256];

  int w = tid >> 6, l = tid & 63;
  int row = bx * 64 + w * 16 + (l & 15);
  int kbase = (l >> 4) * 8;
  bf16x8 afrag[4];
#pragma unroll
  for (int t = 0; t < 4; ++t) {
    const float* ap = ef + (size_t)row * 128 + t * 32 + kbase;
    float4 lo = *(const float4*)ap;
    float4 hi = *(const float4*)(ap + 4);
    bf16x8 a;
    a[0] = (short)f2bu(lo.x); a[1] = (short)f2bu(lo.y);
    a[2] = (short)f2bu(lo.z); a[3] = (short)f2bu(lo.w);
    a[4] = (short)f2bu(hi.x); a[5] = (short)f2bu(hi.y);
    a[6] = (short)f2bu(hi.z); a[7] = (short)f2bu(hi.w);
    afrag[t] = a;
  }
  __syncthreads();

#pragma unroll
  for (int nt = 0; nt < 12; ++nt) {
    f32x4 acc = {0.f, 0.f, 0.f, 0.f};
#pragma unroll
    for (int t = 0; t < 4; ++t) {
      bf16x8 bfrag = *(const bf16x8*)(blds + ((nt * 4 + t) * 64 + l) * 8);
      acc = __builtin_amdgcn_mfma_f32_16x16x32_bf16(bfrag, afrag[t], acc, 0, 0, 0);
    }
    // D is C^T fragment: lane holds C[row][col0..col0+3]
    int col0 = by * 192 + nt * 16 + (l >> 4) * 4;
    float4 bi = *(const float4*)(bc + col0);
    uint2 o;
    o.x = pack2bf(acc[0] + bi.x, acc[1] + bi.y);
    o.y = pack2bf(acc[2] + bi.z, acc[3] + bi.w);
    *(uint2*)(qkvb + (size_t)row * 384 + col0) = o;
  }
}

// out projection: out[23040x128] = updb[23040x128](bf16) x Wp2 + bout, output f32.
__global__ __launch_bounds__(256) void gemm_out_kernel(const ushortT* __restrict__ updb,
                                                       const ushortT* __restrict__ Wp2,
                                                       const float* __restrict__ bout,
                                                       float* __restrict__ outp) {
  __shared__ __align__(16) ushortT blds[16384];  // 32 KB: 8 ntiles x 4 ksteps x 64 x 8
  int tid = threadIdx.x;
  const uint4* src = (const uint4*)Wp2;
  uint4* dst4 = (uint4*)blds;
#pragma unroll
  for (int i = 0; i < 8; ++i) dst4[tid + i * 256] = src[tid + i * 256];

  int w = tid >> 6, l = tid & 63;
  int row = blockIdx.x * 64 + w * 16 + (l & 15);
  bf16x8 afrag[4];
#pragma unroll
  for (int t = 0; t < 4; ++t)
    afrag[t] = *(const bf16x8*)(updb + (size_t)row * 128 + t * 32 + (l >> 4) * 8);
  __syncthreads();

#pragma unroll
  for (int nt = 0; nt < 8; ++nt) {
    f32x4 acc = {0.f, 0.f, 0.f, 0.f};
#pragma unroll
    for (int t = 0; t < 4; ++t) {
      bf16x8 bfrag = *(const bf16x8*)(blds + ((nt * 4 + t) * 64 + l) * 8);
      acc = __builtin_amdgcn_mfma_f32_16x16x32_bf16(bfrag, afrag[t], acc, 0, 0, 0);
    }
    int col0 = nt * 16 + (l >> 4) * 4;
    float4 bi = *(const float4*)(bout + col0);
    float4 o;
    o.x = acc[0] + bi.x; o.y = acc[1] + bi.y; o.z = acc[2] + bi.z; o.w = acc[3] + bi.w;
    *(float4*)(outp + (size_t)row * 128 + col0) = o;
  }
}

// grid (N_NODES, NSPLIT) x 256 threads. Block handles k in [by*KC, by*KC+KC).
__global__ __launch_bounds__(256) void attn_kernel(
    const ushortT* __restrict__ qkvb, const float* __restrict__ g,
    const float* __restrict__ node_trans, const int* __restrict__ edge_index,
    const int* __restrict__ sub_idx, const float* __restrict__ W_db,
    const float* __restrict__ b_db, const float* __restrict__ b_gate,
    ushortT* __restrict__ updb) {
  __shared__ __align__(16) ushortT kvb[KNBR * 256];   // [j][0:128]=k, [j][128:256]=v (bf16)
  __shared__ float bias_lds[KC][SUBK][4];
  __shared__ int sub_lds[KC][SUBK];
  __shared__ float trs[KNBR * 3];
  __shared__ float gg[KNBR * 8];
  int n = blockIdx.x, tid = threadIdx.x;
  int k0b = blockIdx.y * KC;
  int e0 = n * KNBR;

  if (tid < KNBR) {
    int dst = edge_index[e0 + tid];
#pragma unroll
    for (int c = 0; c < 3; ++c) trs[tid * 3 + c] = node_trans[dst * 3 + c];
#pragma unroll
    for (int i = 0; i < 8; ++i) gg[tid * 8 + i] = g[dst * 8 + i];
  }
  for (int i = tid; i < KNBR * 32; i += 256) {
    int j = i >> 5, c = i & 31;
    ((uint4*)kvb)[j * 32 + c] = ((const uint4*)(qkvb + (size_t)(e0 + j) * 384 + 128))[c];
  }
  __syncthreads();

  float4 bgv = *(const float4*)b_gate;
  float4 bdbv = *(const float4*)b_db;
  for (int p = tid; p < KC * SUBK; p += 256) {
    int kl = p / SUBK, s = p % SUBK;
    int kg = k0b + kl;
    if (kg < KNBR) {
      int j = sub_idx[(size_t)(e0 + kg) * SUBK + s];
      sub_lds[kl][s] = j;
      float dx = trs[kg * 3 + 0] - trs[j * 3 + 0] + EPSC;
      float dy = trs[kg * 3 + 1] - trs[j * 3 + 1] + EPSC;
      float dz = trs[kg * 3 + 2] - trs[j * 3 + 2] + EPSC;
      float dist = sqrtf(dx * dx + dy * dy + dz * dz);
      float a0 = 0.f, a1 = 0.f, a2 = 0.f, a3 = 0.f;
#pragma unroll
      for (int r = 0; r < 64; ++r) {
        float t = (dist - r * MU_STEP) * INV_SIGMA;
        float e = __expf(-t * t);
        float4 wv = ((const float4*)W_db)[r];
        a0 += e * wv.x; a1 += e * wv.y; a2 += e * wv.z; a3 += e * wv.w;
      }
      float g1 = gg[kg * 8 + 0] + gg[j * 8 + 4 + 0] + bgv.x;
      float g2 = gg[kg * 8 + 1] + gg[j * 8 + 4 + 1] + bgv.y;
      float g3 = gg[kg * 8 + 2] + gg[j * 8 + 4 + 2] + bgv.z;
      float g4 = gg[kg * 8 + 3] + gg[j * 8 + 4 + 3] + bgv.w;
      bias_lds[kl][s][0] = (a0 + bdbv.x) / (1.0f + __expf(-g1));
      bias_lds[kl][s][1] = (a1 + bdbv.y) / (1.0f + __expf(-g2));
      bias_lds[kl][s][2] = (a2 + bdbv.z) / (1.0f + __expf(-g3));
      bias_lds[kl][s][3] = (a3 + bdbv.w) / (1.0f + __expf(-g4));
    }
  }
  __syncthreads();

  int h = (tid >> 3) & 3, dq = tid & 7;
  int dim0 = h * 32 + dq * 4;
  for (int ki = 0; ki < KC; ki += 8) {
    int kl = ki + ((tid >> 6) << 1) + ((tid >> 5) & 1);
    int kg = k0b + kl;
    if (kg < KNBR) {
      uint2 qu = *(const uint2*)(qkvb + (size_t)(e0 + kg) * 384 + dim0);
      float q0 = bf2f(qu.x & 0xffffu) * INV_SQRT_CZ, q1 = bf2f(qu.x >> 16) * INV_SQRT_CZ;
      float q2 = bf2f(qu.y & 0xffffu) * INV_SQRT_CZ, q3 = bf2f(qu.y >> 16) * INV_SQRT_CZ;
      float logit[SUBK];
#pragma unroll
      for (int s = 0; s < SUBK; ++s) {
        int j = sub_lds[kl][s];
        uint2 ku = *(const uint2*)(kvb + j * 256 + dim0);
        float part = q0 * bf2f(ku.x & 0xffffu) + q1 * bf2f(ku.x >> 16) +
                     q2 * bf2f(ku.y & 0xffffu) + q3 * bf2f(ku.y >> 16);
        part += __shfl_xor(part, 1);
        part += __shfl_xor(part, 2);
        part += __shfl_xor(part, 4);
        logit[s] = part + bias_lds[kl][s][h];
      }
      float m = logit[0];
#pragma unroll
      for (int s = 1; s < SUBK; ++s) m = fmaxf(m, logit[s]);
      float den = 0.f;
#pragma unroll
      for (int s = 0; s < SUBK; ++s) {
        logit[s] = __expf(logit[s] - m);
        den += logit[s];
      }
      float inv = 1.0f / den;
      float acc0 = 0.f, acc1 = 0.f, acc2 = 0.f, acc3 = 0.f;
#pragma unroll
      for (int s = 0; s < SUBK; ++s) {
        int j = sub_lds[kl][s];
        uint2 vu = *(const uint2*)(kvb + j * 256 + 128 + dim0);
        float w = logit[s];
        acc0 += w * bf2f(vu.x & 0xffffu);
        acc1 += w * bf2f(vu.x >> 16);
        acc2 += w * bf2f(vu.y & 0xffffu);
        acc3 += w * bf2f(vu.y >> 16);
      }
      uint2 o;
      o.x = pack2bf(acc0 * inv, acc1 * inv);
      o.y = pack2bf(acc2 * inv, acc3 * inv);
      *(uint2*)(updb + (size_t)(e0 + kg) * 128 + dim0) = o;
    }
  }
}

extern "C" void kernel_launch(void* const* d_in, const int* in_sizes, int n_in, void* d_out,
                              int out_size, void* d_ws, size_t ws_size, hipStream_t stream) {
  const float* nf  = (const float*)d_in[0];
  const float* nt  = (const float*)d_in[1];
  const float* ef  = (const float*)d_in[2];
  const int*   ei  = (const int*)d_in[3];
  const int*   si  = (const int*)d_in[4];
  const float* Wg  = (const float*)d_in[5];
  const float* bg  = (const float*)d_in[6];
  const float* Wdb = (const float*)d_in[7];
  const float* bdb = (const float*)d_in[8];
  const float* Wqk = (const float*)d_in[9];
  const float* bqk = (const float*)d_in[10];
  const float* Wv  = (const float*)d_in[11];
  const float* bv  = (const float*)d_in[12];
  const float* Wout = (const float*)d_in[13];
  const float* bout = (const float*)d_in[14];
  float* out = (float*)d_out;  // f32 output

  // ws layout:
  float* g      = (float*)d_ws;                       // 3072 f32
  float* bc     = g + 3072;                           // 384 f32
  ushortT* Wp1  = (ushortT*)(bc + 384);               // 49152 bf16
  ushortT* Wp2  = Wp1 + 49152;                        // 16384 bf16
  ushortT* qkvb = Wp2 + 16384;                        // NEDGE*384 bf16
  ushortT* updb = qkvb + (size_t)NEDGE * 384;         // NEDGE*128 bf16

  gate_proj_kernel<<<dim3(N_NODES), dim3(64), 0, stream>>>(nf, Wg, g);
  pack_w_kernel<<<dim3(256), dim3(256), 0, stream>>>(Wqk, bqk, Wv, bv, Wout, Wp1, Wp2, bc);
  gemm_qkv_kernel<<<dim3(360, 2), dim3(256), 0, stream>>>(ef, Wp1, bc, qkvb);
  attn_kernel<<<dim3(N_NODES, NSPLIT), dim3(256), 0, stream>>>(qkvb, g, nt, ei, si, Wdb, bdb, bg, updb);
  gemm_out_kernel<<<dim3(360), dim3(256), 0, stream>>>(updb, Wp2, bout, out);
}

// Round 6
// 54.984 us; speedup vs baseline: 5.8764x; 1.1970x over previous
//
#include <hip/hip_runtime.h>
#include <hip/hip_bf16.h>

typedef __hip_bfloat16 bf16;
typedef unsigned short ushortT;
typedef __attribute__((ext_vector_type(8))) short bf16x8;
typedef __attribute__((ext_vector_type(4))) float f32x4;

#define N_NODES 384
#define KNBR 60
#define SUBK 20
#define NHEAD 4
#define NEDGE (N_NODES * KNBR)
#define EPSC 1e-8f
#define INV_SQRT_CZ 0.08838834764831845f   // 1/sqrt(128)
#define MU_STEP (20.0f / 63.0f)            // linspace(0,20,64) step
#define INV_MU_STEP (63.0f / 20.0f)
#define INV_SIGMA 3.2f                     // 1/(20/64)
#define KC 30                              // k-chunk per attn block
#define NSPLIT 2                           // 60/30

__device__ __forceinline__ float bf2f(unsigned int u) {
  return __uint_as_float(u << 16);
}
__device__ __forceinline__ ushortT f2bu(float v) {  // f32 -> bf16 bits, RNE
  union { float f; unsigned int u; } c;
  c.f = v;
  return (ushortT)((c.u + 0x7fffu + ((c.u >> 16) & 1u)) >> 16);
}
__device__ __forceinline__ unsigned int pack2bf(float x, float y) {
  return (unsigned int)f2bu(x) | ((unsigned int)f2bu(y) << 16);
}

// Fused prep: blocks 0..95 = gate projection (4 nodes/block, 64 lanes each);
// blocks 96..351 = weight packing into MFMA fragment order + bias concat.
__global__ __launch_bounds__(256) void prep_kernel(
    const float* __restrict__ nf, const float* __restrict__ Wg, float* __restrict__ g,
    const float* __restrict__ Wqk, const float* __restrict__ bqk,
    const float* __restrict__ Wv, const float* __restrict__ bv,
    const float* __restrict__ Wout,
    ushortT* __restrict__ Wp1, ushortT* __restrict__ Wp2, float* __restrict__ bc) {
  int b = blockIdx.x, tid = threadIdx.x;
  if (b < 96) {
    int n = b * 4 + (tid >> 6), t = tid & 63;
    float a = nf[n * 128 + t];
    float bb = nf[n * 128 + 64 + t];
    float acc[8];
#pragma unroll
    for (int h = 0; h < 4; ++h) {
      acc[h]     = a * Wg[t * 4 + h]         + bb * Wg[(t + 64) * 4 + h];
      acc[4 + h] = a * Wg[(128 + t) * 4 + h] + bb * Wg[(192 + t) * 4 + h];
    }
#pragma unroll
    for (int i = 0; i < 8; ++i)
#pragma unroll
      for (int off = 32; off >= 1; off >>= 1) acc[i] += __shfl_xor(acc[i], off, 64);
    if (t == 0) {
#pragma unroll
      for (int i = 0; i < 8; ++i) g[n * 8 + i] = acc[i];
    }
  } else {
    int i = (b - 96) * 256 + tid;  // 65536 total
    if (i < 49152) {
      int j = i & 7, l = (i >> 3) & 63, t = (i >> 9) & 3;
      int nt = (i >> 11) % 12, ny = (i >> 11) / 12;
      int nn = ny * 192 + nt * 16 + (l & 15);
      int k = t * 32 + (l >> 4) * 8 + j;
      float v = (nn < 256) ? Wqk[k * 256 + nn] : Wv[k * 128 + (nn - 256)];
      Wp1[i] = f2bu(v);
    } else {
      int i2 = i - 49152;  // 16384
      int j = i2 & 7, l = (i2 >> 3) & 63, t = (i2 >> 9) & 3, nt = (i2 >> 11);
      int nn = nt * 16 + (l & 15);
      int k = t * 32 + (l >> 4) * 8 + j;
      Wp2[i2] = f2bu(Wout[k * 128 + nn]);
    }
    if (i < 384) bc[i] = (i < 256) ? bqk[i] : bv[i - 256];
  }
}

// qkv projection: C[23040x384] = bf16(ef[23040x128]) x Wp1 + bc, output bf16.
__global__ __launch_bounds__(256) void gemm_qkv_kernel(const float* __restrict__ ef,
                                                       const ushortT* __restrict__ Wp1,
                                                       const float* __restrict__ bc,
                                                       ushortT* __restrict__ qkvb) {
  __shared__ __align__(16) ushortT blds[24576];  // 48 KB
  int tid = threadIdx.x;
  int bx = blockIdx.x, by = blockIdx.y;
  const uint4* src = (const uint4*)(Wp1 + by * 24576);
  uint4* dst4 = (uint4*)blds;
#pragma unroll
  for (int i = 0; i < 12; ++i) dst4[tid + i * 256] = src[tid + i * 256];

  int w = tid >> 6, l = tid & 63;
  int row = bx * 64 + w * 16 + (l & 15);
  int kbase = (l >> 4) * 8;
  bf16x8 afrag[4];
#pragma unroll
  for (int t = 0; t < 4; ++t) {
    const float* ap = ef + (size_t)row * 128 + t * 32 + kbase;
    float4 lo = *(const float4*)ap;
    float4 hi = *(const float4*)(ap + 4);
    bf16x8 a;
    a[0] = (short)f2bu(lo.x); a[1] = (short)f2bu(lo.y);
    a[2] = (short)f2bu(lo.z); a[3] = (short)f2bu(lo.w);
    a[4] = (short)f2bu(hi.x); a[5] = (short)f2bu(hi.y);
    a[6] = (short)f2bu(hi.z); a[7] = (short)f2bu(hi.w);
    afrag[t] = a;
  }
  __syncthreads();

#pragma unroll
  for (int nt = 0; nt < 12; ++nt) {
    f32x4 acc = {0.f, 0.f, 0.f, 0.f};
#pragma unroll
    for (int t = 0; t < 4; ++t) {
      bf16x8 bfrag = *(const bf16x8*)(blds + ((nt * 4 + t) * 64 + l) * 8);
      acc = __builtin_amdgcn_mfma_f32_16x16x32_bf16(bfrag, afrag[t], acc, 0, 0, 0);
    }
    int col0 = by * 192 + nt * 16 + (l >> 4) * 4;
    float4 bi = *(const float4*)(bc + col0);
    uint2 o;
    o.x = pack2bf(acc[0] + bi.x, acc[1] + bi.y);
    o.y = pack2bf(acc[2] + bi.z, acc[3] + bi.w);
    *(uint2*)(qkvb + (size_t)row * 384 + col0) = o;
  }
}

// out projection: out[23040x128] = updb[23040x128](bf16) x Wp2 + bout, output f32.
__global__ __launch_bounds__(256) void gemm_out_kernel(const ushortT* __restrict__ updb,
                                                       const ushortT* __restrict__ Wp2,
                                                       const float* __restrict__ bout,
                                                       float* __restrict__ outp) {
  __shared__ __align__(16) ushortT blds[16384];  // 32 KB
  int tid = threadIdx.x;
  const uint4* src = (const uint4*)Wp2;
  uint4* dst4 = (uint4*)blds;
#pragma unroll
  for (int i = 0; i < 8; ++i) dst4[tid + i * 256] = src[tid + i * 256];

  int w = tid >> 6, l = tid & 63;
  int row = blockIdx.x * 64 + w * 16 + (l & 15);
  bf16x8 afrag[4];
#pragma unroll
  for (int t = 0; t < 4; ++t)
    afrag[t] = *(const bf16x8*)(updb + (size_t)row * 128 + t * 32 + (l >> 4) * 8);
  __syncthreads();

#pragma unroll
  for (int nt = 0; nt < 8; ++nt) {
    f32x4 acc = {0.f, 0.f, 0.f, 0.f};
#pragma unroll
    for (int t = 0; t < 4; ++t) {
      bf16x8 bfrag = *(const bf16x8*)(blds + ((nt * 4 + t) * 64 + l) * 8);
      acc = __builtin_amdgcn_mfma_f32_16x16x32_bf16(bfrag, afrag[t], acc, 0, 0, 0);
    }
    int col0 = nt * 16 + (l >> 4) * 4;
    float4 bi = *(const float4*)(bout + col0);
    float4 o;
    o.x = acc[0] + bi.x; o.y = acc[1] + bi.y; o.z = acc[2] + bi.z; o.w = acc[3] + bi.w;
    *(float4*)(outp + (size_t)row * 128 + col0) = o;
  }
}

// grid (N_NODES, NSPLIT) x 256 threads. Block handles k in [by*KC, by*KC+KC).
// RBF truncated to +-4 centers around nearest mu (residual < 2e-9).
__global__ __launch_bounds__(256) void attn_kernel(
    const ushortT* __restrict__ qkvb, const float* __restrict__ g,
    const float* __restrict__ node_trans, const int* __restrict__ edge_index,
    const int* __restrict__ sub_idx, const float* __restrict__ W_db,
    const float* __restrict__ b_db, const float* __restrict__ b_gate,
    ushortT* __restrict__ updb) {
  __shared__ __align__(16) ushortT kvb[KNBR * 256];   // 30.7 KB
  __shared__ float bias_lds[KC][SUBK][4];             // 9.6 KB
  __shared__ int sub_lds[KC][SUBK];                   // 2.4 KB
  __shared__ float trs[KNBR * 3];
  __shared__ float gg[KNBR * 8];
  __shared__ __align__(16) float wdb_lds[256];        // 64 x 4
  int n = blockIdx.x, tid = threadIdx.x;
  int k0b = blockIdx.y * KC;
  int e0 = n * KNBR;

  wdb_lds[tid] = W_db[tid];
  if (tid < KNBR) {
    int dst = edge_index[e0 + tid];
#pragma unroll
    for (int c = 0; c < 3; ++c) trs[tid * 3 + c] = node_trans[dst * 3 + c];
#pragma unroll
    for (int i = 0; i < 8; ++i) gg[tid * 8 + i] = g[dst * 8 + i];
  }
  for (int i = tid; i < KNBR * 32; i += 256) {
    int j = i >> 5, c = i & 31;
    ((uint4*)kvb)[j * 32 + c] = ((const uint4*)(qkvb + (size_t)(e0 + j) * 384 + 128))[c];
  }
  __syncthreads();

  float4 bgv = *(const float4*)b_gate;
  float4 bdbv = *(const float4*)b_db;
  for (int p = tid; p < KC * SUBK; p += 256) {
    int kl = p / SUBK, s = p % SUBK;
    int kg = k0b + kl;
    int j = sub_idx[(size_t)(e0 + kg) * SUBK + s];
    sub_lds[kl][s] = j;
    float dx = trs[kg * 3 + 0] - trs[j * 3 + 0] + EPSC;
    float dy = trs[kg * 3 + 1] - trs[j * 3 + 1] + EPSC;
    float dz = trs[kg * 3 + 2] - trs[j * 3 + 2] + EPSC;
    float dist = sqrtf(dx * dx + dy * dy + dz * dz);
    int r0 = (int)(dist * INV_MU_STEP + 0.5f);
    int lo = max(r0 - 4, 0), hi = min(r0 + 4, 63);
    float a0 = 0.f, a1 = 0.f, a2 = 0.f, a3 = 0.f;
    for (int r = lo; r <= hi; ++r) {
      float t = (dist - r * MU_STEP) * INV_SIGMA;
      float e = __expf(-t * t);
      float4 wv = ((const float4*)wdb_lds)[r];
      a0 += e * wv.x; a1 += e * wv.y; a2 += e * wv.z; a3 += e * wv.w;
    }
    float g1 = gg[kg * 8 + 0] + gg[j * 8 + 4 + 0] + bgv.x;
    float g2 = gg[kg * 8 + 1] + gg[j * 8 + 4 + 1] + bgv.y;
    float g3 = gg[kg * 8 + 2] + gg[j * 8 + 4 + 2] + bgv.z;
    float g4 = gg[kg * 8 + 3] + gg[j * 8 + 4 + 3] + bgv.w;
    bias_lds[kl][s][0] = (a0 + bdbv.x) / (1.0f + __expf(-g1));
    bias_lds[kl][s][1] = (a1 + bdbv.y) / (1.0f + __expf(-g2));
    bias_lds[kl][s][2] = (a2 + bdbv.z) / (1.0f + __expf(-g3));
    bias_lds[kl][s][3] = (a3 + bdbv.w) / (1.0f + __expf(-g4));
  }
  __syncthreads();

  int h = (tid >> 3) & 3, dq = tid & 7;
  int dim0 = h * 32 + dq * 4;
  for (int ki = 0; ki < KC; ki += 8) {
    int kl = ki + ((tid >> 6) << 1) + ((tid >> 5) & 1);
    int kg = k0b + kl;
    if (kl < KC) {
      uint2 qu = *(const uint2*)(qkvb + (size_t)(e0 + kg) * 384 + dim0);
      float q0 = bf2f(qu.x & 0xffffu) * INV_SQRT_CZ, q1 = bf2f(qu.x >> 16) * INV_SQRT_CZ;
      float q2 = bf2f(qu.y & 0xffffu) * INV_SQRT_CZ, q3 = bf2f(qu.y >> 16) * INV_SQRT_CZ;
      float logit[SUBK];
#pragma unroll
      for (int s = 0; s < SUBK; ++s) {
        int j = sub_lds[kl][s];
        uint2 ku = *(const uint2*)(kvb + j * 256 + dim0);
        float part = q0 * bf2f(ku.x & 0xffffu) + q1 * bf2f(ku.x >> 16) +
                     q2 * bf2f(ku.y & 0xffffu) + q3 * bf2f(ku.y >> 16);
        part += __shfl_xor(part, 1);
        part += __shfl_xor(part, 2);
        part += __shfl_xor(part, 4);
        logit[s] = part + bias_lds[kl][s][h];
      }
      float m = logit[0];
#pragma unroll
      for (int s = 1; s < SUBK; ++s) m = fmaxf(m, logit[s]);
      float den = 0.f;
#pragma unroll
      for (int s = 0; s < SUBK; ++s) {
        logit[s] = __expf(logit[s] - m);
        den += logit[s];
      }
      float inv = 1.0f / den;
      float acc0 = 0.f, acc1 = 0.f, acc2 = 0.f, acc3 = 0.f;
#pragma unroll
      for (int s = 0; s < SUBK; ++s) {
        int j = sub_lds[kl][s];
        uint2 vu = *(const uint2*)(kvb + j * 256 + 128 + dim0);
        float w = logit[s];
        acc0 += w * bf2f(vu.x & 0xffffu);
        acc1 += w * bf2f(vu.x >> 16);
        acc2 += w * bf2f(vu.y & 0xffffu);
        acc3 += w * bf2f(vu.y >> 16);
      }
      uint2 o;
      o.x = pack2bf(acc0 * inv, acc1 * inv);
      o.y = pack2bf(acc2 * inv, acc3 * inv);
      *(uint2*)(updb + (size_t)(e0 + kg) * 128 + dim0) = o;
    }
  }
}

extern "C" void kernel_launch(void* const* d_in, const int* in_sizes, int n_in, void* d_out,
                              int out_size, void* d_ws, size_t ws_size, hipStream_t stream) {
  const float* nf  = (const float*)d_in[0];
  const float* nt  = (const float*)d_in[1];
  const float* ef  = (const float*)d_in[2];
  const int*   ei  = (const int*)d_in[3];
  const int*   si  = (const int*)d_in[4];
  const float* Wg  = (const float*)d_in[5];
  const float* bg  = (const float*)d_in[6];
  const float* Wdb = (const float*)d_in[7];
  const float* bdb = (const float*)d_in[8];
  const float* Wqk = (const float*)d_in[9];
  const float* bqk = (const float*)d_in[10];
  const float* Wv  = (const float*)d_in[11];
  const float* bv  = (const float*)d_in[12];
  const float* Wout = (const float*)d_in[13];
  const float* bout = (const float*)d_in[14];
  float* out = (float*)d_out;  // f32 output

  float* g      = (float*)d_ws;                       // 3072 f32
  float* bc     = g + 3072;                           // 384 f32
  ushortT* Wp1  = (ushortT*)(bc + 384);               // 49152 bf16
  ushortT* Wp2  = Wp1 + 49152;                        // 16384 bf16
  ushortT* qkvb = Wp2 + 16384;                        // NEDGE*384 bf16
  ushortT* updb = qkvb + (size_t)NEDGE * 384;         // NEDGE*128 bf16

  prep_kernel<<<dim3(352), dim3(256), 0, stream>>>(nf, Wg, g, Wqk, bqk, Wv, bv, Wout,
                                                   Wp1, Wp2, bc);
  gemm_qkv_kernel<<<dim3(360, 2), dim3(256), 0, stream>>>(ef, Wp1, bc, qkvb);
  attn_kernel<<<dim3(N_NODES, NSPLIT), dim3(256), 0, stream>>>(qkvb, g, nt, ei, si, Wdb, bdb,
                                                               bg, updb);
  gemm_out_kernel<<<dim3(360), dim3(256), 0, stream>>>(updb, Wp2, bout, out);
}

// Round 7
// 45.842 us; speedup vs baseline: 7.0483x; 1.1994x over previous
//
#include <hip/hip_runtime.h>
#include <hip/hip_bf16.h>

typedef unsigned short ushortT;
typedef __attribute__((ext_vector_type(8))) short bf16x8;
typedef __attribute__((ext_vector_type(4))) float f32x4;

#define N_NODES 384
#define KNBR 60
#define SUBK 20
#define NEDGE (N_NODES * KNBR)
#define EPSC 1e-8f
#define INV_SQRT_CZ 0.08838834764831845f   // 1/sqrt(128)
#define MU_STEP (20.0f / 63.0f)            // linspace(0,20,64) step
#define INV_MU_STEP (63.0f / 20.0f)
#define INV_SIGMA 3.2f                     // 1/(20/64)

__device__ __forceinline__ float bflo(unsigned int u) { return __uint_as_float(u << 16); }
__device__ __forceinline__ float bfhi(unsigned int u) { return __uint_as_float(u & 0xffff0000u); }
__device__ __forceinline__ ushortT f2bu(float v) {  // f32 -> bf16 bits, RNE
  union { float f; unsigned int u; } c;
  c.f = v;
  return (ushortT)((c.u + 0x7fffu + ((c.u >> 16) & 1u)) >> 16);
}
__device__ __forceinline__ unsigned int pack2bf(float x, float y) {
  return (unsigned int)f2bu(x) | ((unsigned int)f2bu(y) << 16);
}
__device__ __forceinline__ ushortT f2h(float x) {
  _Float16 h = (_Float16)x;
  return __builtin_bit_cast(ushortT, h);
}
__device__ __forceinline__ float h2f(ushortT u) {
  return (float)__builtin_bit_cast(_Float16, u);
}

// Fused prep: blocks 0..95 = gate projection (4 nodes/block, 64 lanes each);
// blocks 96..351 = weight packing into MFMA fragment order + bias concat.
__global__ __launch_bounds__(256) void prep_kernel(
    const float* __restrict__ nf, const float* __restrict__ Wg, float* __restrict__ g,
    const float* __restrict__ Wqk, const float* __restrict__ bqk,
    const float* __restrict__ Wv, const float* __restrict__ bv,
    const float* __restrict__ Wout,
    ushortT* __restrict__ Wp1, ushortT* __restrict__ Wp2, float* __restrict__ bc) {
  int b = blockIdx.x, tid = threadIdx.x;
  if (b < 96) {
    int n = b * 4 + (tid >> 6), t = tid & 63;
    float a = nf[n * 128 + t];
    float bb = nf[n * 128 + 64 + t];
    float acc[8];
#pragma unroll
    for (int h = 0; h < 4; ++h) {
      acc[h]     = a * Wg[t * 4 + h]         + bb * Wg[(t + 64) * 4 + h];
      acc[4 + h] = a * Wg[(128 + t) * 4 + h] + bb * Wg[(192 + t) * 4 + h];
    }
#pragma unroll
    for (int i = 0; i < 8; ++i)
#pragma unroll
      for (int off = 32; off >= 1; off >>= 1) acc[i] += __shfl_xor(acc[i], off, 64);
    if (t == 0) {
#pragma unroll
      for (int i = 0; i < 8; ++i) g[n * 8 + i] = acc[i];
    }
  } else {
    int i = (b - 96) * 256 + tid;  // 65536 total
    if (i < 49152) {
      int j = i & 7, l = (i >> 3) & 63, t = (i >> 9) & 3;
      int nt = (i >> 11) % 12, ny = (i >> 11) / 12;
      int nn = ny * 192 + nt * 16 + (l & 15);
      int k = t * 32 + (l >> 4) * 8 + j;
      float v = (nn < 256) ? Wqk[k * 256 + nn] : Wv[k * 128 + (nn - 256)];
      Wp1[i] = f2bu(v);
    } else {
      int i2 = i - 49152;  // 16384
      int j = i2 & 7, l = (i2 >> 3) & 63, t = (i2 >> 9) & 3, nt = (i2 >> 11);
      int nn = nt * 16 + (l & 15);
      int k = t * 32 + (l >> 4) * 8 + j;
      Wp2[i2] = f2bu(Wout[k * 128 + nn]);
    }
    if (i < 384) bc[i] = (i < 256) ? bqk[i] : bv[i - 256];
  }
}

// One block per node: qkv MFMA projection -> attention -> out MFMA projection.
// 256 thr = 4 waves; wave w owns edge-rows w*16..w*16+15 (rows 60..63 are pad).
__global__ __launch_bounds__(256) void fused_kernel(
    const float* __restrict__ ef, const ushortT* __restrict__ Wp1,
    const ushortT* __restrict__ Wp2, const float* __restrict__ bc,
    const float* __restrict__ bout, const float* __restrict__ g,
    const float* __restrict__ node_trans, const int* __restrict__ edge_index,
    const int* __restrict__ sub_idx, const float* __restrict__ W_db,
    const float* __restrict__ b_db, const float* __restrict__ b_gate,
    float* __restrict__ outp) {
  __shared__ __align__(16) ushortT kvb[KNBR * 256];   // 30720 B, rows XOR-swizzled by (row&7)<<4
  __shared__ __align__(16) ushortT updq[64 * 136];    // 17408 B, q scratch then upd (pad 8/row)
  __shared__ __align__(16) ushortT unionb[4800];      // 9600 B: Bbuf 2x2048 | bias f16 [60][20][4]
  __shared__ ushortT sub_lds[KNBR * SUBK];            // 2400 B
  __shared__ float trs[KNBR * 3];                     // 720 B
  __shared__ float gg[KNBR * 8];                      // 1920 B
  __shared__ __align__(16) float wdb_lds[256];        // 1024 B

  int n = blockIdx.x, tid = threadIdx.x;
  int e0 = n * KNBR;
  int w = tid >> 6, l = tid & 63;
  int lr = l & 15, lc = l >> 4;
  int row = w * 16 + lr;                 // 0..63
  int rowc = min(row, KNBR - 1);

  // ---- phase 0: small staging + A fragments ----
  wdb_lds[tid] = W_db[tid];
  if (tid < KNBR) {
    int dst = edge_index[e0 + tid];
#pragma unroll
    for (int c = 0; c < 3; ++c) trs[tid * 3 + c] = node_trans[dst * 3 + c];
#pragma unroll
    for (int i = 0; i < 8; ++i) gg[tid * 8 + i] = g[dst * 8 + i];
  }
  bf16x8 afrag[4];
#pragma unroll
  for (int t = 0; t < 4; ++t) {
    const float* ap = ef + (size_t)(e0 + rowc) * 128 + t * 32 + lc * 8;
    float4 lo = *(const float4*)ap;
    float4 hi = *(const float4*)(ap + 4);
    bf16x8 a;
    a[0] = (short)f2bu(lo.x); a[1] = (short)f2bu(lo.y);
    a[2] = (short)f2bu(lo.z); a[3] = (short)f2bu(lo.w);
    a[4] = (short)f2bu(hi.x); a[5] = (short)f2bu(hi.y);
    a[6] = (short)f2bu(hi.z); a[7] = (short)f2bu(hi.w);
    afrag[t] = a;
  }

  ushortT* Bb0 = unionb;
  ushortT* Bb1 = unionb + 2048;
  {
    uint4 p = *(const uint4*)(Wp1 + tid * 8);
    *(uint4*)(Bb0 + tid * 8) = p;
  }
  __syncthreads();

  // ---- phase 1: qkv projection, 24 col-tiles of 16 ----
  float qv[32];
#pragma unroll
  for (int T = 0; T < 24; ++T) {
    if (T < 23) {
      uint4 p = *(const uint4*)(Wp1 + (T + 1) * 2048 + tid * 8);
      *(uint4*)(((T & 1) ? Bb0 : Bb1) + tid * 8) = p;   // write the *other* buffer
    }
    const ushortT* bb = (T & 1) ? Bb1 : Bb0;
    f32x4 acc = {0.f, 0.f, 0.f, 0.f};
#pragma unroll
    for (int t = 0; t < 4; ++t) {
      bf16x8 bfrag = *(const bf16x8*)(bb + (t * 64 + l) * 8);
      acc = __builtin_amdgcn_mfma_f32_16x16x32_bf16(bfrag, afrag[t], acc, 0, 0, 0);
    }
    int col0 = T * 16 + lc * 4;
    float4 bi = *(const float4*)(bc + col0);
    if (T < 8) {  // q -> registers (scaled)
      qv[T * 4 + 0] = (acc[0] + bi.x) * INV_SQRT_CZ;
      qv[T * 4 + 1] = (acc[1] + bi.y) * INV_SQRT_CZ;
      qv[T * 4 + 2] = (acc[2] + bi.z) * INV_SQRT_CZ;
      qv[T * 4 + 3] = (acc[3] + bi.w) * INV_SQRT_CZ;
    } else if (row < KNBR) {  // k,v -> kvb (swizzled)
      uint2 o;
      o.x = pack2bf(acc[0] + bi.x, acc[1] + bi.y);
      o.y = pack2bf(acc[2] + bi.z, acc[3] + bi.w);
      int byteoff = ((col0 - 128) * 2) ^ ((row & 7) << 4);
      *(uint2*)((char*)kvb + row * 512 + byteoff) = o;
    }
    __syncthreads();
  }
  // q -> updq scratch (bf16, already scaled)
#pragma unroll
  for (int t = 0; t < 8; ++t) {
    uint2 o;
    o.x = pack2bf(qv[t * 4 + 0], qv[t * 4 + 1]);
    o.y = pack2bf(qv[t * 4 + 2], qv[t * 4 + 3]);
    *(uint2*)(updq + row * 136 + t * 16 + lc * 4) = o;
  }

  // ---- phase 2: bias precompute (dist + truncated RBF + gate) ----
  ushortT* biasb = unionb;  // f16 bits [60][20][4]
  float4 bgv = *(const float4*)b_gate;
  float4 bdbv = *(const float4*)b_db;
  for (int p = tid; p < KNBR * SUBK; p += 256) {
    int kl = p / SUBK, s = p - kl * SUBK;
    int j = sub_idx[(size_t)(e0 + kl) * SUBK + s];
    sub_lds[p] = (ushortT)j;
    float dx = trs[kl * 3 + 0] - trs[j * 3 + 0] + EPSC;
    float dy = trs[kl * 3 + 1] - trs[j * 3 + 1] + EPSC;
    float dz = trs[kl * 3 + 2] - trs[j * 3 + 2] + EPSC;
    float dist = sqrtf(dx * dx + dy * dy + dz * dz);
    int r0 = (int)(dist * INV_MU_STEP + 0.5f);
    int rlo = max(r0 - 4, 0), rhi = min(r0 + 4, 63);
    float a0 = 0.f, a1 = 0.f, a2 = 0.f, a3 = 0.f;
    for (int r = rlo; r <= rhi; ++r) {
      float t = (dist - r * MU_STEP) * INV_SIGMA;
      float e = __expf(-t * t);
      float4 wv = ((const float4*)wdb_lds)[r];
      a0 += e * wv.x; a1 += e * wv.y; a2 += e * wv.z; a3 += e * wv.w;
    }
    float g1 = gg[kl * 8 + 0] + gg[j * 8 + 4 + 0] + bgv.x;
    float g2 = gg[kl * 8 + 1] + gg[j * 8 + 4 + 1] + bgv.y;
    float g3 = gg[kl * 8 + 2] + gg[j * 8 + 4 + 2] + bgv.z;
    float g4 = gg[kl * 8 + 3] + gg[j * 8 + 4 + 3] + bgv.w;
    biasb[p * 4 + 0] = f2h((a0 + bdbv.x) / (1.0f + __expf(-g1)));
    biasb[p * 4 + 1] = f2h((a1 + bdbv.y) / (1.0f + __expf(-g2)));
    biasb[p * 4 + 2] = f2h((a2 + bdbv.z) / (1.0f + __expf(-g3)));
    biasb[p * 4 + 3] = f2h((a3 + bdbv.w) / (1.0f + __expf(-g4)));
  }
  __syncthreads();

  // ---- phase 3: attention. lane = (row=lr, head=lc); full head dot in-lane ----
  const char* kvbase = (const char*)kvb;
  float qh[32];
#pragma unroll
  for (int c = 0; c < 4; ++c) {
    uint4 u = *(const uint4*)(updq + row * 136 + lc * 32 + c * 8);
    qh[c * 8 + 0] = bflo(u.x); qh[c * 8 + 1] = bfhi(u.x);
    qh[c * 8 + 2] = bflo(u.y); qh[c * 8 + 3] = bfhi(u.y);
    qh[c * 8 + 4] = bflo(u.z); qh[c * 8 + 5] = bfhi(u.z);
    qh[c * 8 + 6] = bflo(u.w); qh[c * 8 + 7] = bfhi(u.w);
  }
  float logit[SUBK];
#pragma unroll
  for (int s = 0; s < SUBK; ++s) {
    int j = sub_lds[rowc * SUBK + s];
    int sw = (j & 7) << 4;
    float dot = 0.f;
#pragma unroll
    for (int c = 0; c < 4; ++c) {
      uint4 u = *(const uint4*)(kvbase + j * 512 + ((lc * 64 + c * 16) ^ sw));
      dot += qh[c * 8 + 0] * bflo(u.x) + qh[c * 8 + 1] * bfhi(u.x) +
             qh[c * 8 + 2] * bflo(u.y) + qh[c * 8 + 3] * bfhi(u.y) +
             qh[c * 8 + 4] * bflo(u.z) + qh[c * 8 + 5] * bfhi(u.z) +
             qh[c * 8 + 6] * bflo(u.w) + qh[c * 8 + 7] * bfhi(u.w);
    }
    logit[s] = dot + h2f(biasb[(rowc * SUBK + s) * 4 + lc]);
  }
  float m = logit[0];
#pragma unroll
  for (int s = 1; s < SUBK; ++s) m = fmaxf(m, logit[s]);
  float den = 0.f;
#pragma unroll
  for (int s = 0; s < SUBK; ++s) {
    logit[s] = __expf(logit[s] - m);
    den += logit[s];
  }
  float inv = 1.0f / den;
  float vacc[32];
#pragma unroll
  for (int i = 0; i < 32; ++i) vacc[i] = 0.f;
#pragma unroll
  for (int s = 0; s < SUBK; ++s) {
    int j = sub_lds[rowc * SUBK + s];
    int sw = (j & 7) << 4;
    float wgt = logit[s];
#pragma unroll
    for (int c = 0; c < 4; ++c) {
      uint4 u = *(const uint4*)(kvbase + j * 512 + ((256 + lc * 64 + c * 16) ^ sw));
      vacc[c * 8 + 0] += wgt * bflo(u.x); vacc[c * 8 + 1] += wgt * bfhi(u.x);
      vacc[c * 8 + 2] += wgt * bflo(u.y); vacc[c * 8 + 3] += wgt * bfhi(u.y);
      vacc[c * 8 + 4] += wgt * bflo(u.z); vacc[c * 8 + 5] += wgt * bfhi(u.z);
      vacc[c * 8 + 6] += wgt * bflo(u.w); vacc[c * 8 + 7] += wgt * bfhi(u.w);
    }
  }
  // upd -> updq (overwrites this lane's own q slice; same-lane ordering is safe)
#pragma unroll
  for (int c = 0; c < 4; ++c) {
    uint4 o;
    o.x = pack2bf(vacc[c * 8 + 0] * inv, vacc[c * 8 + 1] * inv);
    o.y = pack2bf(vacc[c * 8 + 2] * inv, vacc[c * 8 + 3] * inv);
    o.z = pack2bf(vacc[c * 8 + 4] * inv, vacc[c * 8 + 5] * inv);
    o.w = pack2bf(vacc[c * 8 + 6] * inv, vacc[c * 8 + 7] * inv);
    *(uint4*)(updq + row * 136 + lc * 32 + c * 8) = o;
  }
  __syncthreads();

  // ---- phase 4: out projection ----
  bf16x8 af2[4];
#pragma unroll
  for (int t = 0; t < 4; ++t)
    af2[t] = *(const bf16x8*)(updq + row * 136 + t * 32 + lc * 8);
  {
    uint4 p = *(const uint4*)(Wp2 + tid * 8);
    *(uint4*)(Bb0 + tid * 8) = p;
  }
  __syncthreads();
#pragma unroll
  for (int T = 0; T < 8; ++T) {
    if (T < 7) {
      uint4 p = *(const uint4*)(Wp2 + (T + 1) * 2048 + tid * 8);
      *(uint4*)(((T & 1) ? Bb0 : Bb1) + tid * 8) = p;
    }
    const ushortT* bb = (T & 1) ? Bb1 : Bb0;
    f32x4 acc = {0.f, 0.f, 0.f, 0.f};
#pragma unroll
    for (int t = 0; t < 4; ++t) {
      bf16x8 bfrag = *(const bf16x8*)(bb + (t * 64 + l) * 8);
      acc = __builtin_amdgcn_mfma_f32_16x16x32_bf16(bfrag, af2[t], acc, 0, 0, 0);
    }
    if (row < KNBR) {
      int col0 = T * 16 + lc * 4;
      float4 bi = *(const float4*)(bout + col0);
      float4 o;
      o.x = acc[0] + bi.x; o.y = acc[1] + bi.y;
      o.z = acc[2] + bi.z; o.w = acc[3] + bi.w;
      *(float4*)(outp + (size_t)(e0 + row) * 128 + col0) = o;
    }
    __syncthreads();
  }
}

extern "C" void kernel_launch(void* const* d_in, const int* in_sizes, int n_in, void* d_out,
                              int out_size, void* d_ws, size_t ws_size, hipStream_t stream) {
  const float* nf  = (const float*)d_in[0];
  const float* nt  = (const float*)d_in[1];
  const float* ef  = (const float*)d_in[2];
  const int*   ei  = (const int*)d_in[3];
  const int*   si  = (const int*)d_in[4];
  const float* Wg  = (const float*)d_in[5];
  const float* bg  = (const float*)d_in[6];
  const float* Wdb = (const float*)d_in[7];
  const float* bdb = (const float*)d_in[8];
  const float* Wqk = (const float*)d_in[9];
  const float* bqk = (const float*)d_in[10];
  const float* Wv  = (const float*)d_in[11];
  const float* bv  = (const float*)d_in[12];
  const float* Wout = (const float*)d_in[13];
  const float* bout = (const float*)d_in[14];
  float* out = (float*)d_out;  // f32 output

  float* g      = (float*)d_ws;                 // 3072 f32
  float* bc     = g + 3072;                     // 384 f32
  ushortT* Wp1  = (ushortT*)(bc + 384);         // 49152 bf16
  ushortT* Wp2  = Wp1 + 49152;                  // 16384 bf16

  prep_kernel<<<dim3(352), dim3(256), 0, stream>>>(nf, Wg, g, Wqk, bqk, Wv, bv, Wout,
                                                   Wp1, Wp2, bc);
  fused_kernel<<<dim3(N_NODES), dim3(256), 0, stream>>>(ef, Wp1, Wp2, bc, bout, g, nt, ei, si,
                                                        Wdb, bdb, bg, out);
}

// Round 8
// 40.205 us; speedup vs baseline: 8.0366x; 1.1402x over previous
//
#include <hip/hip_runtime.h>
#include <hip/hip_bf16.h>

typedef unsigned short ushortT;
typedef __attribute__((ext_vector_type(8))) short bf16x8;
typedef __attribute__((ext_vector_type(4))) float f32x4;

#define N_NODES 384
#define KNBR 60
#define SUBK 20
#define NEDGE (N_NODES * KNBR)
#define EPSC 1e-8f
#define INV_SQRT_CZ 0.08838834764831845f   // 1/sqrt(128)
#define MU_STEP (20.0f / 63.0f)            // linspace(0,20,64) step
#define INV_MU_STEP (63.0f / 20.0f)
#define INV_SIGMA 3.2f                     // 1/(20/64)

__device__ __forceinline__ float bflo(unsigned int u) { return __uint_as_float(u << 16); }
__device__ __forceinline__ float bfhi(unsigned int u) { return __uint_as_float(u & 0xffff0000u); }
__device__ __forceinline__ ushortT f2bu(float v) {  // f32 -> bf16 bits, RNE
  union { float f; unsigned int u; } c;
  c.f = v;
  return (ushortT)((c.u + 0x7fffu + ((c.u >> 16) & 1u)) >> 16);
}
__device__ __forceinline__ unsigned int pack2bf(float x, float y) {
  return (unsigned int)f2bu(x) | ((unsigned int)f2bu(y) << 16);
}
__device__ __forceinline__ ushortT f2h(float x) {
  _Float16 h = (_Float16)x;
  return __builtin_bit_cast(ushortT, h);
}
__device__ __forceinline__ float h2f(ushortT u) {
  return (float)__builtin_bit_cast(_Float16, u);
}

// Fused prep: blocks 0..95 = gate projection (4 nodes/block, 64 lanes each);
// blocks 96..351 = weight packing into MFMA fragment order + bias concat.
__global__ __launch_bounds__(256) void prep_kernel(
    const float* __restrict__ nf, const float* __restrict__ Wg, float* __restrict__ g,
    const float* __restrict__ Wqk, const float* __restrict__ bqk,
    const float* __restrict__ Wv, const float* __restrict__ bv,
    const float* __restrict__ Wout,
    ushortT* __restrict__ Wp1, ushortT* __restrict__ Wp2, float* __restrict__ bc) {
  int b = blockIdx.x, tid = threadIdx.x;
  if (b < 96) {
    int n = b * 4 + (tid >> 6), t = tid & 63;
    float a = nf[n * 128 + t];
    float bb = nf[n * 128 + 64 + t];
    float acc[8];
#pragma unroll
    for (int h = 0; h < 4; ++h) {
      acc[h]     = a * Wg[t * 4 + h]         + bb * Wg[(t + 64) * 4 + h];
      acc[4 + h] = a * Wg[(128 + t) * 4 + h] + bb * Wg[(192 + t) * 4 + h];
    }
#pragma unroll
    for (int i = 0; i < 8; ++i)
#pragma unroll
      for (int off = 32; off >= 1; off >>= 1) acc[i] += __shfl_xor(acc[i], off, 64);
    if (t == 0) {
#pragma unroll
      for (int i = 0; i < 8; ++i) g[n * 8 + i] = acc[i];
    }
  } else {
    int i = (b - 96) * 256 + tid;  // 65536 total
    if (i < 49152) {
      int j = i & 7, l = (i >> 3) & 63, t = (i >> 9) & 3;
      int nt = (i >> 11) % 12, ny = (i >> 11) / 12;
      int nn = ny * 192 + nt * 16 + (l & 15);
      int k = t * 32 + (l >> 4) * 8 + j;
      float v = (nn < 256) ? Wqk[k * 256 + nn] : Wv[k * 128 + (nn - 256)];
      Wp1[i] = f2bu(v);
    } else {
      int i2 = i - 49152;  // 16384
      int j = i2 & 7, l = (i2 >> 3) & 63, t = (i2 >> 9) & 3, nt = (i2 >> 11);
      int nn = nt * 16 + (l & 15);
      int k = t * 32 + (l >> 4) * 8 + j;
      Wp2[i2] = f2bu(Wout[k * 128 + nn]);
    }
    if (i < 384) bc[i] = (i < 256) ? bqk[i] : bv[i - 256];
  }
}

// One block per node, 512 threads (8 waves, two 4-wave groups).
// Phase 1: qkv projection, B-fragments DIRECT from global (no LDS staging, no barriers);
//   group g handles col-tiles T = g*12 .. g*12+11. q (T<8, scaled) -> updq; k/v -> kvb.
// Phase 2: truncated-RBF bias -> biasb (f16).
// Phase 3: attention; lane = (row, head, dim-half); 16-dim in-lane dot + 1 shfl_xor.
// Phase 4: out projection; group g handles col-tiles g*4..g*4+3, B-frags direct global.
__global__ __launch_bounds__(512, 4) void fused_kernel(
    const float* __restrict__ ef, const ushortT* __restrict__ Wp1,
    const ushortT* __restrict__ Wp2, const float* __restrict__ bc,
    const float* __restrict__ bout, const float* __restrict__ g,
    const float* __restrict__ node_trans, const int* __restrict__ edge_index,
    const int* __restrict__ sub_idx, const float* __restrict__ W_db,
    const float* __restrict__ b_db, const float* __restrict__ b_gate,
    float* __restrict__ outp) {
  __shared__ __align__(16) ushortT kvb[KNBR * 256];     // 30720 B, row-xor-swizzled
  __shared__ __align__(16) ushortT updq[64 * 136];      // 17408 B (q then upd, pad 8/row)
  __shared__ __align__(16) ushortT biasb[KNBR * SUBK * 4];  // 9600 B, f16
  __shared__ ushortT sub_lds[KNBR * SUBK];              // 2400 B
  __shared__ float trs[KNBR * 3];                       // 720 B
  __shared__ float gg[KNBR * 8];                        // 1920 B

  int n = blockIdx.x, tid = threadIdx.x;
  int e0 = n * KNBR;
  int w = tid >> 6, l = tid & 63;
  int lr = l & 15, lc = l >> 4;
  int rowA = (w & 3) * 16 + lr;          // 0..63 (rows 60..63 pad)
  int rowAc = min(rowA, KNBR - 1);

  // ---- phase 0: stage trs/gg + load A fragments ----
  if (tid < KNBR) {
    int dst = edge_index[e0 + tid];
#pragma unroll
    for (int c = 0; c < 3; ++c) trs[tid * 3 + c] = node_trans[dst * 3 + c];
#pragma unroll
    for (int i = 0; i < 8; ++i) gg[tid * 8 + i] = g[dst * 8 + i];
  }
  bf16x8 afrag[4];
#pragma unroll
  for (int t = 0; t < 4; ++t) {
    const float* ap = ef + (size_t)(e0 + rowAc) * 128 + t * 32 + lc * 8;
    float4 lo = *(const float4*)ap;
    float4 hi = *(const float4*)(ap + 4);
    bf16x8 a;
    a[0] = (short)f2bu(lo.x); a[1] = (short)f2bu(lo.y);
    a[2] = (short)f2bu(lo.z); a[3] = (short)f2bu(lo.w);
    a[4] = (short)f2bu(hi.x); a[5] = (short)f2bu(hi.y);
    a[6] = (short)f2bu(hi.z); a[7] = (short)f2bu(hi.w);
    afrag[t] = a;
  }

  // ---- phase 1: qkv projection, 12 col-tiles per group, no barriers ----
  int Tbase = (tid >> 8) * 12;
#pragma unroll
  for (int Ti = 0; Ti < 12; ++Ti) {
    int T = Tbase + Ti;
    f32x4 acc = {0.f, 0.f, 0.f, 0.f};
#pragma unroll
    for (int t = 0; t < 4; ++t) {
      bf16x8 bfrag = *(const bf16x8*)(Wp1 + ((T * 4 + t) * 64 + l) * 8);
      acc = __builtin_amdgcn_mfma_f32_16x16x32_bf16(bfrag, afrag[t], acc, 0, 0, 0);
    }
    int col0 = T * 16 + lc * 4;
    float4 bi = *(const float4*)(bc + col0);
    float o0 = acc[0] + bi.x, o1 = acc[1] + bi.y;
    float o2 = acc[2] + bi.z, o3 = acc[3] + bi.w;
    if (T < 8) {  // q: scale, straight to updq (bf16)
      uint2 o;
      o.x = pack2bf(o0 * INV_SQRT_CZ, o1 * INV_SQRT_CZ);
      o.y = pack2bf(o2 * INV_SQRT_CZ, o3 * INV_SQRT_CZ);
      *(uint2*)(updq + rowA * 136 + col0) = o;
    } else if (rowA < KNBR) {  // k,v -> kvb (swizzled)
      uint2 o;
      o.x = pack2bf(o0, o1);
      o.y = pack2bf(o2, o3);
      int byteoff = ((col0 - 128) * 2) ^ ((rowA & 7) << 4);
      *(uint2*)((char*)kvb + rowA * 512 + byteoff) = o;
    }
  }
  __syncthreads();  // A: trs/gg visible for phase 2

  // ---- phase 2: bias precompute (dist + truncated RBF + gate) ----
  float4 bgv = *(const float4*)b_gate;
  float4 bdbv = *(const float4*)b_db;
  for (int p = tid; p < KNBR * SUBK; p += 512) {
    int kl = p / SUBK, s = p - kl * SUBK;
    int j = sub_idx[(size_t)(e0 + kl) * SUBK + s];
    sub_lds[p] = (ushortT)j;
    float dx = trs[kl * 3 + 0] - trs[j * 3 + 0] + EPSC;
    float dy = trs[kl * 3 + 1] - trs[j * 3 + 1] + EPSC;
    float dz = trs[kl * 3 + 2] - trs[j * 3 + 2] + EPSC;
    float dist = sqrtf(dx * dx + dy * dy + dz * dz);
    int r0 = (int)(dist * INV_MU_STEP + 0.5f);
    int rlo = max(r0 - 4, 0), rhi = min(r0 + 4, 63);
    float a0 = 0.f, a1 = 0.f, a2 = 0.f, a3 = 0.f;
    for (int r = rlo; r <= rhi; ++r) {
      float t = (dist - r * MU_STEP) * INV_SIGMA;
      float e = __expf(-t * t);
      float4 wv = ((const float4*)W_db)[r];
      a0 += e * wv.x; a1 += e * wv.y; a2 += e * wv.z; a3 += e * wv.w;
    }
    float g1 = gg[kl * 8 + 0] + gg[j * 8 + 4 + 0] + bgv.x;
    float g2 = gg[kl * 8 + 1] + gg[j * 8 + 4 + 1] + bgv.y;
    float g3 = gg[kl * 8 + 2] + gg[j * 8 + 4 + 2] + bgv.z;
    float g4 = gg[kl * 8 + 3] + gg[j * 8 + 4 + 3] + bgv.w;
    biasb[p * 4 + 0] = f2h((a0 + bdbv.x) / (1.0f + __expf(-g1)));
    biasb[p * 4 + 1] = f2h((a1 + bdbv.y) / (1.0f + __expf(-g2)));
    biasb[p * 4 + 2] = f2h((a2 + bdbv.z) / (1.0f + __expf(-g3)));
    biasb[p * 4 + 3] = f2h((a3 + bdbv.w) / (1.0f + __expf(-g4)));
  }
  __syncthreads();  // B: kvb + updq(q) + biasb + sub_lds visible

  // ---- phase 3: attention. lane = (row=tid>>3, head=(tid>>1)&3, dhalf=tid&1) ----
  int row3 = tid >> 3, h = (tid >> 1) & 3, dh = tid & 1;
  int row3c = min(row3, KNBR - 1);
  const char* kvbase = (const char*)kvb;
  float qh[16];
  {
    const ushortT* qp = updq + row3 * 136 + h * 32 + dh * 16;
    uint4 u0 = *(const uint4*)qp;
    uint4 u1 = *(const uint4*)(qp + 8);
    qh[0] = bflo(u0.x); qh[1] = bfhi(u0.x); qh[2] = bflo(u0.y); qh[3] = bfhi(u0.y);
    qh[4] = bflo(u0.z); qh[5] = bfhi(u0.z); qh[6] = bflo(u0.w); qh[7] = bfhi(u0.w);
    qh[8] = bflo(u1.x); qh[9] = bfhi(u1.x); qh[10] = bflo(u1.y); qh[11] = bfhi(u1.y);
    qh[12] = bflo(u1.z); qh[13] = bfhi(u1.z); qh[14] = bflo(u1.w); qh[15] = bfhi(u1.w);
  }
  float logit[SUBK];
#pragma unroll
  for (int s = 0; s < SUBK; ++s) {
    int j = sub_lds[row3c * SUBK + s];
    int sw = (j & 7) << 4;
    float dot = 0.f;
#pragma unroll
    for (int c = 0; c < 2; ++c) {
      uint4 u = *(const uint4*)(kvbase + j * 512 + ((h * 64 + dh * 32 + c * 16) ^ sw));
      dot += qh[c * 8 + 0] * bflo(u.x) + qh[c * 8 + 1] * bfhi(u.x) +
             qh[c * 8 + 2] * bflo(u.y) + qh[c * 8 + 3] * bfhi(u.y) +
             qh[c * 8 + 4] * bflo(u.z) + qh[c * 8 + 5] * bfhi(u.z) +
             qh[c * 8 + 6] * bflo(u.w) + qh[c * 8 + 7] * bfhi(u.w);
    }
    dot += __shfl_xor(dot, 1);
    logit[s] = dot + h2f(biasb[(row3c * SUBK + s) * 4 + h]);
  }
  float m = logit[0];
#pragma unroll
  for (int s = 1; s < SUBK; ++s) m = fmaxf(m, logit[s]);
  float den = 0.f;
#pragma unroll
  for (int s = 0; s < SUBK; ++s) {
    logit[s] = __expf(logit[s] - m);
    den += logit[s];
  }
  float inv = 1.0f / den;
  float vacc[16];
#pragma unroll
  for (int i = 0; i < 16; ++i) vacc[i] = 0.f;
#pragma unroll
  for (int s = 0; s < SUBK; ++s) {
    int j = sub_lds[row3c * SUBK + s];
    int sw = (j & 7) << 4;
    float wgt = logit[s];
#pragma unroll
    for (int c = 0; c < 2; ++c) {
      uint4 u = *(const uint4*)(kvbase + j * 512 + ((256 + h * 64 + dh * 32 + c * 16) ^ sw));
      vacc[c * 8 + 0] += wgt * bflo(u.x); vacc[c * 8 + 1] += wgt * bfhi(u.x);
      vacc[c * 8 + 2] += wgt * bflo(u.y); vacc[c * 8 + 3] += wgt * bfhi(u.y);
      vacc[c * 8 + 4] += wgt * bflo(u.z); vacc[c * 8 + 5] += wgt * bfhi(u.z);
      vacc[c * 8 + 6] += wgt * bflo(u.w); vacc[c * 8 + 7] += wgt * bfhi(u.w);
    }
  }
#pragma unroll
  for (int c = 0; c < 2; ++c) {
    uint4 o;
    o.x = pack2bf(vacc[c * 8 + 0] * inv, vacc[c * 8 + 1] * inv);
    o.y = pack2bf(vacc[c * 8 + 2] * inv, vacc[c * 8 + 3] * inv);
    o.z = pack2bf(vacc[c * 8 + 4] * inv, vacc[c * 8 + 5] * inv);
    o.w = pack2bf(vacc[c * 8 + 6] * inv, vacc[c * 8 + 7] * inv);
    *(uint4*)(updq + row3 * 136 + h * 32 + dh * 16 + c * 8) = o;
  }
  __syncthreads();  // C: upd visible

  // ---- phase 4: out projection, 4 col-tiles per group ----
  bf16x8 af2[4];
#pragma unroll
  for (int t = 0; t < 4; ++t)
    af2[t] = *(const bf16x8*)(updq + rowA * 136 + t * 32 + lc * 8);
  int T4base = (tid >> 8) * 4;
#pragma unroll
  for (int Ti = 0; Ti < 4; ++Ti) {
    int T = T4base + Ti;
    f32x4 acc = {0.f, 0.f, 0.f, 0.f};
#pragma unroll
    for (int t = 0; t < 4; ++t) {
      bf16x8 bfrag = *(const bf16x8*)(Wp2 + ((T * 4 + t) * 64 + l) * 8);
      acc = __builtin_amdgcn_mfma_f32_16x16x32_bf16(bfrag, af2[t], acc, 0, 0, 0);
    }
    if (rowA < KNBR) {
      int col0 = T * 16 + lc * 4;
      float4 bi = *(const float4*)(bout + col0);
      float4 o;
      o.x = acc[0] + bi.x; o.y = acc[1] + bi.y;
      o.z = acc[2] + bi.z; o.w = acc[3] + bi.w;
      *(float4*)(outp + (size_t)(e0 + rowA) * 128 + col0) = o;
    }
  }
}

extern "C" void kernel_launch(void* const* d_in, const int* in_sizes, int n_in, void* d_out,
                              int out_size, void* d_ws, size_t ws_size, hipStream_t stream) {
  const float* nf  = (const float*)d_in[0];
  const float* nt  = (const float*)d_in[1];
  const float* ef  = (const float*)d_in[2];
  const int*   ei  = (const int*)d_in[3];
  const int*   si  = (const int*)d_in[4];
  const float* Wg  = (const float*)d_in[5];
  const float* bg  = (const float*)d_in[6];
  const float* Wdb = (const float*)d_in[7];
  const float* bdb = (const float*)d_in[8];
  const float* Wqk = (const float*)d_in[9];
  const float* bqk = (const float*)d_in[10];
  const float* Wv  = (const float*)d_in[11];
  const float* bv  = (const float*)d_in[12];
  const float* Wout = (const float*)d_in[13];
  const float* bout = (const float*)d_in[14];
  float* out = (float*)d_out;  // f32 output

  float* g      = (float*)d_ws;                 // 3072 f32
  float* bc     = g + 3072;                     // 384 f32
  ushortT* Wp1  = (ushortT*)(bc + 384);         // 49152 bf16
  ushortT* Wp2  = Wp1 + 49152;                  // 16384 bf16

  prep_kernel<<<dim3(352), dim3(256), 0, stream>>>(nf, Wg, g, Wqk, bqk, Wv, bv, Wout,
                                                   Wp1, Wp2, bc);
  fused_kernel<<<dim3(N_NODES), dim3(512), 0, stream>>>(ef, Wp1, Wp2, bc, bout, g, nt, ei, si,
                                                        Wdb, bdb, bg, out);
}